// Round 14
// baseline (97.875 us; speedup 1.0000x reference)
//
#include <hip/hip_runtime.h>
#include <hip/hip_bf16.h>

typedef int    i32x4 __attribute__((ext_vector_type(4)));
typedef float  f32x4 __attribute__((ext_vector_type(4)));

#define NPIX  100352   // 32*56*56
#define CIN   256
#define COUT  256

#define QC    4.75f
#define QINV  (127.0f/QC)
#define QDEQ  (QC/127.0f)

#define WBT_OFF 0u
#define XQ_OFF  (1024u*1024u)
#define WS_NEED_I8 ((size_t)XQ_OFF + (size_t)32*3364*256)   // ~28.6 MB

#define BAR() do { asm volatile("" ::: "memory"); __builtin_amdgcn_s_barrier(); asm volatile("" ::: "memory"); } while(0)

// ---- merged prepass: blocks [0,13456) quantize+pad x; blocks [13456,15760) binarize w ----
__global__ __launch_bounds__(256) void prep_kernel(const float* __restrict__ x,
                                                   signed char* __restrict__ xq,
                                                   const float* __restrict__ w,
                                                   signed char* __restrict__ wbt) {
    const int bid = blockIdx.x;
    if (bid < 13456) {
        const int g = bid * 256 + threadIdx.x;          // chunk of 8 channels
        const int prow = g >> 5, cseg = g & 31;
        const int b = prow / 3364, rr = prow % 3364;
        const int ph = rr / 58, pw = rr % 58;
        int2 pack = {0, 0};
        if (ph >= 1 && ph <= 56 && pw >= 1 && pw <= 56) {
            const size_t s = ((size_t)b * 3136 + (size_t)(ph - 1) * 56 + (pw - 1)) * 256 + cseg * 8;
            const f32x4 a = *(const f32x4*)(x + s);
            const f32x4 c = *(const f32x4*)(x + s + 4);
            unsigned lo = 0, hi = 0;
            #pragma unroll
            for (int j = 0; j < 4; ++j) {
                int qa = (int)rintf(fminf(fmaxf(a[j], -QC), QC) * QINV);
                int qc = (int)rintf(fminf(fmaxf(c[j], -QC), QC) * QINV);
                lo |= (unsigned)(qa & 255) << (8 * j);
                hi |= (unsigned)(qc & 255) << (8 * j);
            }
            pack.x = (int)lo; pack.y = (int)hi;
        }
        *(int2*)(xq + (size_t)g * 8) = pack;
    } else {
        const int rc   = bid - 13456;                   // tap*256 + cin
        const int cout = threadIdx.x;
        const float v  = w[(size_t)rc * COUT + cout];
        const signed char s = (v > 0.f) ? 1 : ((v < 0.f) ? -1 : 0);
        const int tap = rc >> 8;
        const int cin = rc & 255;
        wbt[((size_t)(tap * COUT + cout)) * CIN + cin] = s;
    }
}

__device__ __forceinline__ void gll16(const signed char* g, signed char* l) {
    __builtin_amdgcn_global_load_lds(
        (const __attribute__((address_space(1))) void*)g,
        (__attribute__((address_space(3))) void*)l, 16, 0, 0);
}

__device__ __forceinline__ void mfma_i8(i32x4& acc, i32x4 a, i32x4 b) {
    asm("v_mfma_i32_16x16x64_i8 %0, %1, %2, %0" : "+v"(acc) : "v"(a), "v"(b));
}

// =====  128x64 i8 kernel, BK=128, 3 blocks/CU (48 KB LDS), R6-frozen geometry  =====
// LDS: A0(16K) B0(8K) A1(16K) B1(8K) = 48 KB. 128B rows, 8-slot XOR swizzle.
#define SA0 0
#define SB0 16384
#define SA1 24576
#define SB1 40960

#define STAGE_A(REG, TS) do {                                                        \
    const int tap_ = (TS) >> 1;                                                      \
    const int dh1_ = (tap_ * 11) >> 5;  /* tap/3 */                                  \
    const int off_ = ((dh1_ - 1) * 58 + (tap_ - dh1_ * 3 - 1)) * 256 + (((TS) & 1) << 7); \
    _Pragma("unroll")                                                                \
    for (int j_ = 0; j_ < 4; ++j_) gll16(pA[j_] + off_, &lds[(REG) + dOfA[j_]]);     \
} while (0)

// B: 64 rows x 128B per buffer; wave w stages rows w*16..w*16+15 (2 issues of 8 rows)
#define STAGE_B(REG, TS) do {                                                        \
    const signed char* s_ = wbt + (((TS) >> 1) << 16) + (((TS) & 1) << 7);           \
    gll16(s_ + bOf[0], &lds[(REG) + dOfB0]);                                         \
    gll16(s_ + bOf[1], &lds[(REG) + dOfB1]);                                         \
} while (0)

__global__ __launch_bounds__(256, 3) void conv4i(const signed char* __restrict__ xq,
                                                 const signed char* __restrict__ wbt,
                                                 float* __restrict__ out) {
    __shared__ signed char lds[49152];

    const int tid  = threadIdx.x;
    const int lane = tid & 63;
    const int wave = tid >> 6;                  // 0..3
    const int l3 = lane >> 3, l7 = lane & 7;
    const int srcslot = l7 ^ l3;                // source swizzle involution (8 slots x 16B)
    const int lr = lane & 15, kseg = lane >> 4;

    // 3136 blocks = 8 XCD chunks x 392; bn fastest (A-tile L2 reuse within XCD)
    const int bid = blockIdx.x;
    const int L   = (bid & 7) * 392 + (bid >> 3);
    const int bm  = L >> 2;                     // 0..783 (128-pixel tile)
    const int bn  = L & 3;                      // 0..3   (64-cout tile)

    // ---- A staging: wave w owns rows w*32..w*32+31, 4 issues of 8 rows ----
    const signed char* pA[4];
    int dOfA[4];
    #pragma unroll
    for (int j = 0; j < 4; ++j) {
        const int rb = wave * 32 + j * 8;
        dOfA[j] = rb * 128;                     // wave-uniform LDS byte offset
        const int r = rb + l3;                  // per-lane row
        const int p = bm * 128 + r;
        const int b = p / 3136, rem = p % 3136;
        const int hh = rem / 56, ww = rem % 56;
        pA[j] = xq + ((size_t)b * 3364 + (size_t)(hh + 1) * 58 + (ww + 1)) * 256
                   + srcslot * 16;
    }
    // ---- B staging: wave w owns rows w*16..w*16+15, 2 issues of 8 rows ----
    const int dOfB0 = (wave * 16) * 128;
    const int dOfB1 = (wave * 16 + 8) * 128;
    int bOf[2];
    #pragma unroll
    for (int j = 0; j < 2; ++j)
        bOf[j] = (bn * 64 + wave * 16 + j * 8 + l3) * 256 + srcslot * 16;

    // ---- frag read byte offsets (128B rows, 8-slot XOR — frozen R6 pattern) ----
    const int m_base = (wave >> 1) * 64;
    const int n_base = (wave & 1) * 32;
    const int slot0 = ((kseg)     ^ (lr & 7)) * 16;
    const int slot1 = ((4 + kseg) ^ (lr & 7)) * 16;
    const int aB = (m_base + lr) * 128;
    const int bB = (n_base + lr) * 128;
    const int aK0 = aB + slot0, aK1 = aB + slot1;
    const int bK0 = bB + slot0, bK1 = bB + slot1;

    i32x4 acc[4][2];
    #pragma unroll
    for (int f = 0; f < 4; ++f)
        #pragma unroll
        for (int n = 0; n < 2; ++n)
            acc[f][n] = (i32x4){0, 0, 0, 0};

    // ---- prologue: B0(0)[2], A0(0)[4], B1(1)[2]; drain t0, keep B1 (2) in flight ----
    STAGE_B(SB0, 0);
    STAGE_A(SA0, 0);
    STAGE_B(SB1, 1);
    asm volatile("s_waitcnt vmcnt(2)" ::: "memory");
    BAR();

    i32x4 bk0[2], bk1[2];
    i32x4 af[8];

    // R6 ledger, counts rescaled (B=2 issues): vmcnt(2) at ph2/ph4 ends drains
    // {B(next)=2, A(next)=4} leaving next B (2) in flight. Last iter: ph2 vmcnt(0).
    for (int i = 0; i < 9; ++i) {
        const bool last = (i == 8);
        const int te = 2 * i + 2;
        const int to = 2 * i + 3;

        // ===== ph1: read A(buf0, both kf) + B(buf0, both kf); stage A1(2i+1); MFMA k0 =====
        {
            #pragma unroll
            for (int f = 0; f < 4; ++f) {
                af[f]     = *(const i32x4*)&lds[SA0 + aK0 + f * 2048];
                af[f + 4] = *(const i32x4*)&lds[SA0 + aK1 + f * 2048];
            }
            #pragma unroll
            for (int n = 0; n < 2; ++n) {
                bk0[n] = *(const i32x4*)&lds[SB0 + bK0 + n * 2048];
                bk1[n] = *(const i32x4*)&lds[SB0 + bK1 + n * 2048];
            }
            STAGE_A(SA1, 2 * i + 1);
            __builtin_amdgcn_s_setprio(1);
            #pragma unroll
            for (int f = 0; f < 4; ++f)
                #pragma unroll
                for (int n = 0; n < 2; ++n) mfma_i8(acc[f][n], af[f], bk0[n]);
            __builtin_amdgcn_s_setprio(0);
            BAR();
        }
        // ===== ph2: MFMA k1 (regs); stage B0(te); vmcnt(2) =====
        {
            if (!last) {
                STAGE_B(SB0, te);
                asm volatile("s_waitcnt vmcnt(2)" ::: "memory");
            } else {
                asm volatile("s_waitcnt vmcnt(0)" ::: "memory");
            }
            __builtin_amdgcn_s_setprio(1);
            #pragma unroll
            for (int f = 0; f < 4; ++f)
                #pragma unroll
                for (int n = 0; n < 2; ++n) mfma_i8(acc[f][n], af[f + 4], bk1[n]);
            __builtin_amdgcn_s_setprio(0);
            BAR();
        }
        // ===== ph3: read A(buf1, both kf) + B(buf1); stage A0(te); MFMA k0 =====
        {
            #pragma unroll
            for (int f = 0; f < 4; ++f) {
                af[f]     = *(const i32x4*)&lds[SA1 + aK0 + f * 2048];
                af[f + 4] = *(const i32x4*)&lds[SA1 + aK1 + f * 2048];
            }
            #pragma unroll
            for (int n = 0; n < 2; ++n) {
                bk0[n] = *(const i32x4*)&lds[SB1 + bK0 + n * 2048];
                bk1[n] = *(const i32x4*)&lds[SB1 + bK1 + n * 2048];
            }
            if (!last) STAGE_A(SA0, te);
            __builtin_amdgcn_s_setprio(1);
            #pragma unroll
            for (int f = 0; f < 4; ++f)
                #pragma unroll
                for (int n = 0; n < 2; ++n) mfma_i8(acc[f][n], af[f], bk0[n]);
            __builtin_amdgcn_s_setprio(0);
            BAR();
        }
        // ===== ph4: MFMA k1 (regs); stage B1(to); vmcnt(2) =====
        {
            if (!last) {
                STAGE_B(SB1, to);
                asm volatile("s_waitcnt vmcnt(2)" ::: "memory");
            }
            __builtin_amdgcn_s_setprio(1);
            #pragma unroll
            for (int f = 0; f < 4; ++f)
                #pragma unroll
                for (int n = 0; n < 2; ++n) mfma_i8(acc[f][n], af[f + 4], bk1[n]);
            __builtin_amdgcn_s_setprio(0);
            BAR();
        }
    }

    // ---- epilogue: C/D map col=lane&15, row=(lane>>4)*4+j; dequant ----
    const int row0 = bm * 128 + m_base + (lane >> 4) * 4;
    const int col0 = bn * 64 + n_base + lr;
    #pragma unroll
    for (int f = 0; f < 4; ++f)
        #pragma unroll
        for (int n = 0; n < 2; ++n) {
            const int r = row0 + f * 16;
            const int c = col0 + n * 16;
            #pragma unroll
            for (int j = 0; j < 4; ++j)
                out[(size_t)(r + j) * COUT + c] = QDEQ * (float)acc[f][n][j];
        }
}

// =====================  fallback (tiny ws): bf16 reg-staged  =====================
__global__ void binw_bf16(const float* __restrict__ w, __bf16* __restrict__ wbt) {
    const int cout = threadIdx.x;
    const int rc   = blockIdx.x;
    const float v  = w[(size_t)rc * COUT + cout];
    const float s  = (v > 0.f) ? 1.f : ((v < 0.f) ? -1.f : 0.f);
    wbt[((size_t)((rc >> 8) * COUT + cout)) * CIN + (rc & 255)] = (__bf16)s;
}

__global__ __launch_bounds__(512) void conv_fb(const float* __restrict__ x,
                                               const __bf16* __restrict__ wbt,
                                               float* __restrict__ out) {
    __shared__ __bf16 Alds[128][72];
    __shared__ __bf16 Blds[256][72];
    typedef __bf16 bf8 __attribute__((ext_vector_type(8)));

    const int tid  = threadIdx.x;
    const int lane = tid & 63;
    const int wave = tid >> 6;
    const int m_base = (wave >> 2) * 64;
    const int n_base = (wave & 3) * 64;
    const int lr = lane & 15;
    const int kb = (lane >> 4) * 8;

    const int arow = tid >> 2;
    const int aseg = tid & 3;
    const int p    = blockIdx.x * 128 + arow;
    const int rem  = p % 3136;
    const int h    = rem / 56;
    const int wc   = rem % 56;

    f32x4 acc[4][4];
    #pragma unroll
    for (int i = 0; i < 4; ++i)
        #pragma unroll
        for (int j = 0; j < 4; ++j)
            acc[i][j] = (f32x4){0.f, 0.f, 0.f, 0.f};

    for (int tap = 0; tap < 9; ++tap) {
        const int dh = tap / 3 - 1;
        const int dw = tap % 3 - 1;
        const bool valid = ((unsigned)(h + dh) < 56u) && ((unsigned)(wc + dw) < 56u);
        const long aoff = ((long)p + (long)dh * 56 + dw) * CIN + aseg * 16;
        const __bf16* bsrc = wbt + (size_t)tap * COUT * CIN;

        #pragma unroll
        for (int ks = 0; ks < 4; ++ks) {
            const int c0 = ks * 64;
            __syncthreads();
            f32x4 f0, f1, f2, f3;
            if (valid) {
                const f32x4* s4 = (const f32x4*)(x + aoff + c0);
                f0 = s4[0]; f1 = s4[1]; f2 = s4[2]; f3 = s4[3];
            } else {
                f0 = f1 = f2 = f3 = (f32x4){0.f, 0.f, 0.f, 0.f};
            }
            bf8 v0, v1;
            #pragma unroll
            for (int j = 0; j < 4; ++j) {
                v0[j] = (__bf16)f0[j]; v0[j + 4] = (__bf16)f1[j];
                v1[j] = (__bf16)f2[j]; v1[j + 4] = (__bf16)f3[j];
            }
            *(bf8*)&Alds[arow][aseg * 16]     = v0;
            *(bf8*)&Alds[arow][aseg * 16 + 8] = v1;
            #pragma unroll
            for (int i = 0; i < 4; ++i) {
                const int chunk = tid + i * 512;
                const int row = chunk >> 3;
                const int cs  = chunk & 7;
                *(uint4*)&Blds[row][cs * 8] = *(const uint4*)(bsrc + row * CIN + c0 + cs * 8);
            }
            __syncthreads();

            bf8 af[4][2], bfr[4][2];
            #pragma unroll
            for (int mf = 0; mf < 4; ++mf)
                #pragma unroll
                for (int kf = 0; kf < 2; ++kf)
                    af[mf][kf] = *(const bf8*)&Alds[m_base + mf * 16 + lr][kf * 32 + kb];
            #pragma unroll
            for (int nf = 0; nf < 4; ++nf)
                #pragma unroll
                for (int kf = 0; kf < 2; ++kf)
                    bfr[nf][kf] = *(const bf8*)&Blds[n_base + nf * 16 + lr][kf * 32 + kb];
            #pragma unroll
            for (int kf = 0; kf < 2; ++kf)
                #pragma unroll
                for (int mf = 0; mf < 4; ++mf)
                    #pragma unroll
                    for (int nf = 0; nf < 4; ++nf)
                        acc[mf][nf] = __builtin_amdgcn_mfma_f32_16x16x32_bf16(
                            af[mf][kf], bfr[nf][kf], acc[mf][nf], 0, 0, 0);
        }
    }
    #pragma unroll
    for (int mf = 0; mf < 4; ++mf)
        #pragma unroll
        for (int nf = 0; nf < 4; ++nf) {
            const int r0 = blockIdx.x * 128 + m_base + mf * 16 + (lane >> 4) * 4;
            const int c  = n_base + nf * 16 + lr;
            #pragma unroll
            for (int j = 0; j < 4; ++j)
                out[(size_t)(r0 + j) * COUT + c] = acc[mf][nf][j];
        }
}

extern "C" void kernel_launch(void* const* d_in, const int* in_sizes, int n_in,
                              void* d_out, int out_size, void* d_ws, size_t ws_size,
                              hipStream_t stream) {
    const float* x = (const float*)d_in[0];
    const float* w = (const float*)d_in[1];
    float* out = (float*)d_out;
    char* ws = (char*)d_ws;

    if (ws_size >= WS_NEED_I8) {
        signed char* wbt = (signed char*)(ws + WBT_OFF);
        signed char* xq  = (signed char*)(ws + XQ_OFF);
        prep_kernel<<<13456 + 2304, 256, 0, stream>>>(x, xq, w, wbt);
        conv4i<<<3136, 256, 0, stream>>>(xq, wbt, out);
    } else {
        __bf16* wbt = (__bf16*)(ws + WBT_OFF);
        binw_bf16<<<9 * CIN, COUT, 0, stream>>>(w, wbt);
        conv_fb<<<NPIX / 128, 512, 0, stream>>>(x, wbt, out);
    }
}

// Round 15
// 89.352 us; speedup vs baseline: 1.0954x; 1.0954x over previous
//
#include <hip/hip_runtime.h>
#include <hip/hip_bf16.h>

typedef int    i32x4 __attribute__((ext_vector_type(4)));
typedef float  f32x4 __attribute__((ext_vector_type(4)));

#define NPIX  100352   // 32*56*56
#define CIN   256
#define COUT  256

#define QC    4.75f
#define QINV  (127.0f/QC)
#define QDEQ  (QC/127.0f)

#define WBT_OFF 0u
#define XQ_OFF  (1024u*1024u)
#define WS_NEED_I8 ((size_t)XQ_OFF + (size_t)32*3364*256)   // ~28.6 MB

#define BAR() do { asm volatile("" ::: "memory"); __builtin_amdgcn_s_barrier(); asm volatile("" ::: "memory"); } while(0)

// ---- merged prepass: blocks [0,13456) quantize+pad x; blocks [13456,15760) binarize w ----
__global__ __launch_bounds__(256) void prep_kernel(const float* __restrict__ x,
                                                   signed char* __restrict__ xq,
                                                   const float* __restrict__ w,
                                                   signed char* __restrict__ wbt) {
    const int bid = blockIdx.x;
    if (bid < 13456) {
        const int g = bid * 256 + threadIdx.x;          // chunk of 8 channels
        const int prow = g >> 5, cseg = g & 31;
        const int b = prow / 3364, rr = prow % 3364;
        const int ph = rr / 58, pw = rr % 58;
        int2 pack = {0, 0};
        if (ph >= 1 && ph <= 56 && pw >= 1 && pw <= 56) {
            const size_t s = ((size_t)b * 3136 + (size_t)(ph - 1) * 56 + (pw - 1)) * 256 + cseg * 8;
            const f32x4 a = *(const f32x4*)(x + s);
            const f32x4 c = *(const f32x4*)(x + s + 4);
            unsigned lo = 0, hi = 0;
            #pragma unroll
            for (int j = 0; j < 4; ++j) {
                int qa = (int)rintf(fminf(fmaxf(a[j], -QC), QC) * QINV);
                int qc = (int)rintf(fminf(fmaxf(c[j], -QC), QC) * QINV);
                lo |= (unsigned)(qa & 255) << (8 * j);
                hi |= (unsigned)(qc & 255) << (8 * j);
            }
            pack.x = (int)lo; pack.y = (int)hi;
        }
        *(int2*)(xq + (size_t)g * 8) = pack;
    } else {
        const int rc   = bid - 13456;                   // tap*256 + cin
        const int cout = threadIdx.x;
        const float v  = w[(size_t)rc * COUT + cout];
        const signed char s = (v > 0.f) ? 1 : ((v < 0.f) ? -1 : 0);
        const int tap = rc >> 8;
        const int cin = rc & 255;
        wbt[((size_t)(tap * COUT + cout)) * CIN + cin] = s;
    }
}

__device__ __forceinline__ void gll16(const signed char* g, signed char* l) {
    __builtin_amdgcn_global_load_lds(
        (const __attribute__((address_space(1))) void*)g,
        (__attribute__((address_space(3))) void*)l, 16, 0, 0);
}

__device__ __forceinline__ void mfma_i8(i32x4& acc, i32x4 a, i32x4 b) {
    asm("v_mfma_i32_16x16x64_i8 %0, %1, %2, %0" : "+v"(acc) : "v"(a), "v"(b));
}

// =====  4-phase 128x128 i8 kernel, BK=128, 2 blocks/CU (R10 base + k1-frag hoist)  =====
// LDS byte offsets: A0,B0,A1,B1 each 128 rows x 128 B = 16 KB (total 64 KB)
// Geometry (rows/slots/swizzle) IDENTICAL to the round-6/round-10 zero-conflict kernel.
#define SA0 0
#define SB0 16384
#define SA1 32768
#define SB1 49152

#define STAGE_A(REG, TS) do {                                                        \
    const int tap_ = (TS) >> 1;                                                      \
    const int dh1_ = (tap_ * 11) >> 5;  /* tap/3 */                                  \
    const int off_ = ((dh1_ - 1) * 58 + (tap_ - dh1_ * 3 - 1)) * 256 + (((TS) & 1) << 7); \
    _Pragma("unroll")                                                                \
    for (int j_ = 0; j_ < 4; ++j_) gll16(pA[j_] + off_, &lds[(REG) + dOf[j_]]);      \
} while (0)

#define STAGE_B(REG, TS) do {                                                        \
    const signed char* s_ = wbt + (((TS) >> 1) << 16) + (((TS) & 1) << 7);           \
    _Pragma("unroll")                                                                \
    for (int j_ = 0; j_ < 4; ++j_) gll16(s_ + bOf[j_], &lds[(REG) + dOf[j_]]);       \
} while (0)

__global__ __launch_bounds__(256, 2) void conv4i(const signed char* __restrict__ xq,
                                                 const signed char* __restrict__ wbt,
                                                 float* __restrict__ out) {
    __shared__ signed char lds[65536];

    const int tid  = threadIdx.x;
    const int lane = tid & 63;
    const int wave = tid >> 6;                  // 0..3
    const int l3 = lane >> 3, l7 = lane & 7;
    const int srcslot = l7 ^ l3;                // source swizzle involution (8 slots x 16B)
    const int lr = lane & 15, kseg = lane >> 4;

    // 1568 blocks = 8 XCD chunks x 196; chunked bijective swizzle
    const int bid = blockIdx.x;
    const int L   = (bid & 7) * 196 + (bid >> 3);
    const int bm  = L >> 1;                     // 0..783 (128-pixel tile)
    const int bn  = L & 1;                      // 0..1   (128-cout tile)

    // ---- staging geometry: wave w owns rows w*32..w*32+31, 4 issues of 8 rows ----
    const signed char* pA[4];
    int bOf[4], dOf[4];
    #pragma unroll
    for (int j = 0; j < 4; ++j) {
        const int rb = wave * 32 + j * 8;
        dOf[j] = rb * 128;                      // wave-uniform LDS byte offset
        const int r = rb + l3;                  // per-lane row
        bOf[j] = (bn * 128 + r) * 256 + srcslot * 16;
        const int p = bm * 128 + r;
        const int b = p / 3136, rem = p % 3136;
        const int hh = rem / 56, ww = rem % 56;
        pA[j] = xq + ((size_t)b * 3364 + (size_t)(hh + 1) * 58 + (ww + 1)) * 256
                   + srcslot * 16;
    }

    // ---- frag read byte offsets (within each 128x128B region) ----
    const int m_base = (wave >> 1) * 64;
    const int n_base = (wave & 1) * 64;
    const int slot0 = ((kseg)     ^ (lr & 7)) * 16;
    const int slot1 = ((4 + kseg) ^ (lr & 7)) * 16;
    const int aB = (m_base + lr) * 128;
    const int bB = (n_base + lr) * 128;
    const int aK0 = aB + slot0, aK1 = aB + slot1;
    const int bK0 = bB + slot0, bK1 = bB + slot1;

    i32x4 acc[4][4];
    #pragma unroll
    for (int f = 0; f < 4; ++f)
        #pragma unroll
        for (int n = 0; n < 4; ++n)
            acc[f][n] = (i32x4){0, 0, 0, 0};

    // ---- prologue: B0(0), A0(0), B1(1) = 12 issues; drain t0, keep B1 in flight ----
    STAGE_B(SB0, 0);
    STAGE_A(SA0, 0);
    STAGE_B(SB1, 1);
    asm volatile("s_waitcnt vmcnt(4)" ::: "memory");
    BAR();

    i32x4 bk0[4], bk1[4];
    i32x4 af[8];   // both k-halves of A, prefetched together (static indices only)

    // Ledger identical to R10 (FIFO-verified). k1 A-frags read in the preceding
    // even phase, hiding their LDS latency under the even phase's 16 MFMAs.
    for (int i = 0; i < 9; ++i) {
        const bool last = (i == 8);
        const int te = 2 * i + 2;
        const int to = 2 * i + 3;

        // ===== ph1: read A(buf0, both kf) + all B(buf0); stage A1(2i+1); MFMA k0 =====
        {
            #pragma unroll
            for (int f = 0; f < 4; ++f) {
                af[f]     = *(const i32x4*)&lds[SA0 + aK0 + f * 2048];
                af[f + 4] = *(const i32x4*)&lds[SA0 + aK1 + f * 2048];
            }
            #pragma unroll
            for (int n = 0; n < 4; ++n) {
                bk0[n] = *(const i32x4*)&lds[SB0 + bK0 + n * 2048];
                bk1[n] = *(const i32x4*)&lds[SB0 + bK1 + n * 2048];
            }
            STAGE_A(SA1, 2 * i + 1);
            __builtin_amdgcn_s_setprio(1);
            #pragma unroll
            for (int f = 0; f < 4; ++f)
                #pragma unroll
                for (int n = 0; n < 4; ++n) mfma_i8(acc[f][n], af[f], bk0[n]);
            __builtin_amdgcn_s_setprio(0);
            BAR();
        }
        // ===== ph2: MFMA k1 (frags already in regs); stage B0(te); vmcnt(4) =====
        {
            if (!last) {
                STAGE_B(SB0, te);
                asm volatile("s_waitcnt vmcnt(4)" ::: "memory");
            } else {
                asm volatile("s_waitcnt vmcnt(0)" ::: "memory");
            }
            __builtin_amdgcn_s_setprio(1);
            #pragma unroll
            for (int f = 0; f < 4; ++f)
                #pragma unroll
                for (int n = 0; n < 4; ++n) mfma_i8(acc[f][n], af[f + 4], bk1[n]);
            __builtin_amdgcn_s_setprio(0);
            BAR();
        }
        // ===== ph3: read A(buf1, both kf) + all B(buf1); stage A0(te); MFMA k0 =====
        {
            #pragma unroll
            for (int f = 0; f < 4; ++f) {
                af[f]     = *(const i32x4*)&lds[SA1 + aK0 + f * 2048];
                af[f + 4] = *(const i32x4*)&lds[SA1 + aK1 + f * 2048];
            }
            #pragma unroll
            for (int n = 0; n < 4; ++n) {
                bk0[n] = *(const i32x4*)&lds[SB1 + bK0 + n * 2048];
                bk1[n] = *(const i32x4*)&lds[SB1 + bK1 + n * 2048];
            }
            if (!last) STAGE_A(SA0, te);
            __builtin_amdgcn_s_setprio(1);
            #pragma unroll
            for (int f = 0; f < 4; ++f)
                #pragma unroll
                for (int n = 0; n < 4; ++n) mfma_i8(acc[f][n], af[f], bk0[n]);
            __builtin_amdgcn_s_setprio(0);
            BAR();
        }
        // ===== ph4: MFMA k1 (regs); stage B1(to); vmcnt(4) =====
        {
            if (!last) {
                STAGE_B(SB1, to);
                asm volatile("s_waitcnt vmcnt(4)" ::: "memory");
            }
            __builtin_amdgcn_s_setprio(1);
            #pragma unroll
            for (int f = 0; f < 4; ++f)
                #pragma unroll
                for (int n = 0; n < 4; ++n) mfma_i8(acc[f][n], af[f + 4], bk1[n]);
            __builtin_amdgcn_s_setprio(0);
            BAR();
        }
    }

    // ---- epilogue: C/D map col=lane&15, row=(lane>>4)*4+j; dequant ----
    const int row0 = bm * 128 + m_base + (lane >> 4) * 4;
    const int col0 = bn * 128 + n_base + lr;
    #pragma unroll
    for (int f = 0; f < 4; ++f)
        #pragma unroll
        for (int n = 0; n < 4; ++n) {
            const int r = row0 + f * 16;
            const int c = col0 + n * 16;
            #pragma unroll
            for (int j = 0; j < 4; ++j)
                out[(size_t)(r + j) * COUT + c] = QDEQ * (float)acc[f][n][j];
        }
}

// =====================  fallback (tiny ws): bf16 reg-staged  =====================
__global__ void binw_bf16(const float* __restrict__ w, __bf16* __restrict__ wbt) {
    const int cout = threadIdx.x;
    const int rc   = blockIdx.x;
    const float v  = w[(size_t)rc * COUT + cout];
    const float s  = (v > 0.f) ? 1.f : ((v < 0.f) ? -1.f : 0.f);
    wbt[((size_t)((rc >> 8) * COUT + cout)) * CIN + (rc & 255)] = (__bf16)s;
}

__global__ __launch_bounds__(512) void conv_fb(const float* __restrict__ x,
                                               const __bf16* __restrict__ wbt,
                                               float* __restrict__ out) {
    __shared__ __bf16 Alds[128][72];
    __shared__ __bf16 Blds[256][72];
    typedef __bf16 bf8 __attribute__((ext_vector_type(8)));

    const int tid  = threadIdx.x;
    const int lane = tid & 63;
    const int wave = tid >> 6;
    const int m_base = (wave >> 2) * 64;
    const int n_base = (wave & 3) * 64;
    const int lr = lane & 15;
    const int kb = (lane >> 4) * 8;

    const int arow = tid >> 2;
    const int aseg = tid & 3;
    const int p    = blockIdx.x * 128 + arow;
    const int rem  = p % 3136;
    const int h    = rem / 56;
    const int wc   = rem % 56;

    f32x4 acc[4][4];
    #pragma unroll
    for (int i = 0; i < 4; ++i)
        #pragma unroll
        for (int j = 0; j < 4; ++j)
            acc[i][j] = (f32x4){0.f, 0.f, 0.f, 0.f};

    for (int tap = 0; tap < 9; ++tap) {
        const int dh = tap / 3 - 1;
        const int dw = tap % 3 - 1;
        const bool valid = ((unsigned)(h + dh) < 56u) && ((unsigned)(wc + dw) < 56u);
        const long aoff = ((long)p + (long)dh * 56 + dw) * CIN + aseg * 16;
        const __bf16* bsrc = wbt + (size_t)tap * COUT * CIN;

        #pragma unroll
        for (int ks = 0; ks < 4; ++ks) {
            const int c0 = ks * 64;
            __syncthreads();
            f32x4 f0, f1, f2, f3;
            if (valid) {
                const f32x4* s4 = (const f32x4*)(x + aoff + c0);
                f0 = s4[0]; f1 = s4[1]; f2 = s4[2]; f3 = s4[3];
            } else {
                f0 = f1 = f2 = f3 = (f32x4){0.f, 0.f, 0.f, 0.f};
            }
            bf8 v0, v1;
            #pragma unroll
            for (int j = 0; j < 4; ++j) {
                v0[j] = (__bf16)f0[j]; v0[j + 4] = (__bf16)f1[j];
                v1[j] = (__bf16)f2[j]; v1[j + 4] = (__bf16)f3[j];
            }
            *(bf8*)&Alds[arow][aseg * 16]     = v0;
            *(bf8*)&Alds[arow][aseg * 16 + 8] = v1;
            #pragma unroll
            for (int i = 0; i < 4; ++i) {
                const int chunk = tid + i * 512;
                const int row = chunk >> 3;
                const int cs  = chunk & 7;
                *(uint4*)&Blds[row][cs * 8] = *(const uint4*)(bsrc + row * CIN + c0 + cs * 8);
            }
            __syncthreads();

            bf8 af[4][2], bfr[4][2];
            #pragma unroll
            for (int mf = 0; mf < 4; ++mf)
                #pragma unroll
                for (int kf = 0; kf < 2; ++kf)
                    af[mf][kf] = *(const bf8*)&Alds[m_base + mf * 16 + lr][kf * 32 + kb];
            #pragma unroll
            for (int nf = 0; nf < 4; ++nf)
                #pragma unroll
                for (int kf = 0; kf < 2; ++kf)
                    bfr[nf][kf] = *(const bf8*)&Blds[n_base + nf * 16 + lr][kf * 32 + kb];
            #pragma unroll
            for (int kf = 0; kf < 2; ++kf)
                #pragma unroll
                for (int mf = 0; mf < 4; ++mf)
                    #pragma unroll
                    for (int nf = 0; nf < 4; ++nf)
                        acc[mf][nf] = __builtin_amdgcn_mfma_f32_16x16x32_bf16(
                            af[mf][kf], bfr[nf][kf], acc[mf][nf], 0, 0, 0);
        }
    }
    #pragma unroll
    for (int mf = 0; mf < 4; ++mf)
        #pragma unroll
        for (int nf = 0; nf < 4; ++nf) {
            const int r0 = blockIdx.x * 128 + m_base + mf * 16 + (lane >> 4) * 4;
            const int c  = n_base + nf * 16 + lr;
            #pragma unroll
            for (int j = 0; j < 4; ++j)
                out[(size_t)(r0 + j) * COUT + c] = acc[mf][nf][j];
        }
}

extern "C" void kernel_launch(void* const* d_in, const int* in_sizes, int n_in,
                              void* d_out, int out_size, void* d_ws, size_t ws_size,
                              hipStream_t stream) {
    const float* x = (const float*)d_in[0];
    const float* w = (const float*)d_in[1];
    float* out = (float*)d_out;
    char* ws = (char*)d_ws;

    if (ws_size >= WS_NEED_I8) {
        signed char* wbt = (signed char*)(ws + WBT_OFF);
        signed char* xq  = (signed char*)(ws + XQ_OFF);
        prep_kernel<<<13456 + 2304, 256, 0, stream>>>(x, xq, w, wbt);
        conv4i<<<1568, 256, 0, stream>>>(xq, wbt, out);
    } else {
        __bf16* wbt = (__bf16*)(ws + WBT_OFF);
        binw_bf16<<<9 * CIN, COUT, 0, stream>>>(w, wbt);
        conv_fb<<<NPIX / 128, 512, 0, stream>>>(x, wbt, out);
    }
}